// Round 11
// baseline (91.870 us; speedup 1.0000x reference)
//
#include <hip/hip_runtime.h>
#include <math.h>

// x [B=1024, S=256, E=4] fp32. One block = one batch (256 threads, 4 waves).
// One-pass softmax, per-row bound m_hat = sqrt(|q|^2 * max|k|^2) in exp2
// domain (m_hat row-uniform -> cross-wave merge is a plain sum).
// Wave-autonomous hot loop: wave w's lanes computed k/v for rows w*64+lane
// == exactly chunk w -- they stay in REGISTERS. Key values broadcast with
// v_readlane (VALU/scalar path, per-SIMD) instead of wave-uniform
// ds_read_b128 (CU-shared LDS pipe = R7/R8's measured wall). Hot loop has
// ZERO memory instructions; arithmetic is R5's packed v_pk_fma_f32 form.
// R11 = R10 with the compile fix: readlane goes through a bit-cast wrapper
// (builtin is int(int,int)); loop stays FULLY unrolled so lane indices are
// compile-time literals (v_readlane_b32 s, v, imm).
constexpr int S  = 256;
constexpr int E  = 4;
constexpr int H1 = 8;
constexpr int H2 = 4;
constexpr int NW  = 4;        // waves per block
constexpr int PPW = 32;       // key pairs per wave (64 own keys)
constexpr int R   = 4;        // rows per lane

typedef float v2f __attribute__((ext_vector_type(2)));

__device__ __forceinline__ v2f fma2(v2f a, v2f b, v2f c) {
    return __builtin_elementwise_fma(a, b, c);
}
__device__ __forceinline__ float fast_tanh(float x) {
    const float z = __builtin_amdgcn_exp2f(x * 2.88539008f);  // e^(2x)
    return 1.f - 2.f * __builtin_amdgcn_rcpf(z + 1.f);        // inf-safe
}
__device__ __forceinline__ float bcast(float v, int l) {
    return __int_as_float(__builtin_amdgcn_readlane(__float_as_int(v), l));
}

__global__ __launch_bounds__(256, 4) void attn_mlp_kernel(
    const float* __restrict__ x,
    const float* __restrict__ Wq, const float* __restrict__ Wk, const float* __restrict__ Wv,
    const float* __restrict__ W1, const float* __restrict__ b1,
    const float* __restrict__ W2, const float* __restrict__ b2,
    const float* __restrict__ W3, const float* __restrict__ b3,
    float* __restrict__ out)
{
    const int b    = blockIdx.x;
    const int tid  = threadIdx.x;
    const int w    = tid >> 6;
    const int lane = tid & 63;

    __shared__ float4 q_lds[S];         // 4 KB
    __shared__ float4 acc_lds[NW][S];   // 16 KB
    __shared__ float  l_lds[NW][S];     // 4 KB
    __shared__ float  kmax_lds[NW];

    // ---- Phase 1: q/k/v for row tid; k/v REMAIN IN REGISTERS ----
    const float4 xr = *reinterpret_cast<const float4*>(x + ((size_t)b * S + tid) * E);
    const float xv[E] = {xr.x, xr.y, xr.z, xr.w};
    float4 kreg, vreg;
    {
        float4 q;
        float* qp = &q.x; float* kp = &kreg.x; float* vp = &vreg.x;
        float kk = 0.f;
        #pragma unroll
        for (int e = 0; e < E; ++e) {
            float aq = 0.f, ak = 0.f, av = 0.f;
            #pragma unroll
            for (int i = 0; i < E; ++i) {
                aq = fmaf(xv[i], Wq[i * E + e], aq);
                ak = fmaf(xv[i], Wk[i * E + e], ak);
                av = fmaf(xv[i], Wv[i * E + e], av);
            }
            qp[e] = aq * (0.5f * 1.44269504f);  // fold 1/sqrt(E), log2(e)
            kp[e] = ak;
            vp[e] = av;
            kk = fmaf(ak, ak, kk);
        }
        q_lds[tid] = q;

        #pragma unroll
        for (int off = 32; off > 0; off >>= 1)
            kk = fmaxf(kk, __shfl_xor(kk, off));
        if (lane == 0) kmax_lds[w] = kk;
    }
    __syncthreads();

    const float kmax2 = fmaxf(fmaxf(kmax_lds[0], kmax_lds[1]),
                              fmaxf(kmax_lds[2], kmax_lds[3]));

    // ---- per-lane rows {lane + 64*rr}: splat q and -m_hat into pairs ----
    v2f qx2[R], qy2[R], qz2[R], qw2[R], mh2[R];
    #pragma unroll
    for (int rr = 0; rr < R; ++rr) {
        const float4 q = q_lds[lane + 64 * rr];
        const float qq = fmaf(q.x, q.x, fmaf(q.y, q.y, fmaf(q.z, q.z, q.w * q.w)));
        const float mh = sqrtf(qq * kmax2);  // >= every scaled score
        qx2[rr] = v2f{q.x, q.x};
        qy2[rr] = v2f{q.y, q.y};
        qz2[rr] = v2f{q.z, q.z};
        qw2[rr] = v2f{q.w, q.w};
        mh2[rr] = v2f{-mh, -mh};
    }

    v2f l2[R], a0[R], a1[R], a2[R], a3[R];
    #pragma unroll
    for (int rr = 0; rr < R; ++rr) {
        l2[rr] = v2f{0.f, 0.f};
        a0[rr] = a1[rr] = a2[rr] = a3[rr] = v2f{0.f, 0.f};
    }

    // ---- Phase 2: scan own 32 key pairs; readlane with LITERAL lanes ----
    #pragma unroll
    for (int jp = 0; jp < PPW; ++jp) {
        // jp is compile-time (full unroll) -> lane indices are literals
        const v2f kx = {bcast(kreg.x, 2 * jp), bcast(kreg.x, 2 * jp + 1)};
        const v2f ky = {bcast(kreg.y, 2 * jp), bcast(kreg.y, 2 * jp + 1)};
        const v2f kz = {bcast(kreg.z, 2 * jp), bcast(kreg.z, 2 * jp + 1)};
        const v2f kw = {bcast(kreg.w, 2 * jp), bcast(kreg.w, 2 * jp + 1)};
        const v2f vx = {bcast(vreg.x, 2 * jp), bcast(vreg.x, 2 * jp + 1)};
        const v2f vy = {bcast(vreg.y, 2 * jp), bcast(vreg.y, 2 * jp + 1)};
        const v2f vz = {bcast(vreg.z, 2 * jp), bcast(vreg.z, 2 * jp + 1)};
        const v2f vw = {bcast(vreg.w, 2 * jp), bcast(vreg.w, 2 * jp + 1)};
        #pragma unroll
        for (int rr = 0; rr < R; ++rr) {
            v2f s2 = fma2(qw2[rr], kw, mh2[rr]);
            s2 = fma2(qz2[rr], kz, s2);
            s2 = fma2(qy2[rr], ky, s2);
            s2 = fma2(qx2[rr], kx, s2);
            const v2f p2 = {__builtin_amdgcn_exp2f(s2.x),
                            __builtin_amdgcn_exp2f(s2.y)};  // s2 <= 0
            l2[rr] += p2;
            a0[rr] = fma2(p2, vx, a0[rr]);
            a1[rr] = fma2(p2, vy, a1[rr]);
            a2[rr] = fma2(p2, vz, a2[rr]);
            a3[rr] = fma2(p2, vw, a3[rr]);
        }
    }

    // ---- merge partials: plain per-wave stores, no atomics ----
    #pragma unroll
    for (int rr = 0; rr < R; ++rr) {
        const int row = lane + 64 * rr;
        acc_lds[w][row] = make_float4(a0[rr].x + a0[rr].y,
                                      a1[rr].x + a1[rr].y,
                                      a2[rr].x + a2[rr].y,
                                      a3[rr].x + a3[rr].y);
        l_lds[w][row] = l2[rr].x + l2[rr].y;
    }
    __syncthreads();

    // ---- Phase 3: plain-sum merge for row tid, then MLP ----
    float lsum = 0.f;
    float ax = 0.f, ay = 0.f, az = 0.f, aw = 0.f;
    #pragma unroll
    for (int ww = 0; ww < NW; ++ww) {
        lsum += l_lds[ww][tid];
        const float4 a4 = acc_lds[ww][tid];
        ax += a4.x; ay += a4.y; az += a4.z; aw += a4.w;
    }
    const float inv = 1.0f / lsum;
    const float a[E] = {ax * inv, ay * inv, az * inv, aw * inv};

    float h1[H1];
    #pragma unroll
    for (int o = 0; o < H1; ++o) {
        float s = b1[o];
        #pragma unroll
        for (int i = 0; i < E; ++i) s = fmaf(a[i], W1[i * H1 + o], s);
        h1[o] = fast_tanh(s);
    }
    float h2[H2];
    #pragma unroll
    for (int o = 0; o < H2; ++o) {
        float s = b2[o];
        #pragma unroll
        for (int i = 0; i < H1; ++i) s = fmaf(h1[i], W2[i * H2 + o], s);
        h2[o] = fast_tanh(s);
    }
    float r = b3[0];
    #pragma unroll
    for (int i = 0; i < H2; ++i) r = fmaf(h2[i], W3[i], r);

    out[(size_t)b * S + tid] = r;
}

extern "C" void kernel_launch(void* const* d_in, const int* in_sizes, int n_in,
                              void* d_out, int out_size, void* d_ws, size_t ws_size,
                              hipStream_t stream) {
    const float* x  = (const float*)d_in[0];
    const float* Wq = (const float*)d_in[1];
    const float* Wk = (const float*)d_in[2];
    const float* Wv = (const float*)d_in[3];
    const float* W1 = (const float*)d_in[4];
    const float* b1 = (const float*)d_in[5];
    const float* W2 = (const float*)d_in[6];
    const float* b2 = (const float*)d_in[7];
    const float* W3 = (const float*)d_in[8];
    const float* b3 = (const float*)d_in[9];
    float* out = (float*)d_out;

    const int B = in_sizes[0] / (S * E);   // 1024
    attn_mlp_kernel<<<dim3(B), dim3(256), 0, stream>>>(
        x, Wq, Wk, Wv, W1, b1, W2, b2, W3, b3, out);
}

// Round 12
// 88.681 us; speedup vs baseline: 1.0360x; 1.0360x over previous
//
#include <hip/hip_runtime.h>
#include <math.h>

// x [B=1024, S=256, E=4] fp32. One block = one batch (256 threads, 4 waves).
// One-pass softmax, per-row bound m_hat = sqrt(|q|^2 * max|k|^2) in exp2
// domain (m_hat row-uniform -> cross-wave merge is a plain sum).
// Packed hot loop: keys in PAIRS, pair-transposed LDS records, v_pk_fma_f32.
// This is the best-measured structure (R7, 89.2 us end-to-end). Four
// structural variants (scalar LDS / packed LDS / wrap-prefetch / readlane
// broadcast) all converge at 29-32 us kernel: the loop is fp32-VALU
// THROUGHPUT-bound (pk_fma_f32 = 4 cyc/wave64 -- packing does not raise
// fp32 FLOP rate; ~600M FMA-ops + 67M quarter-rate exps on the 157 TF
// vector pipe; no fp32-input MFMA on CDNA4 and E=4 << K=16 anyway).
constexpr int S  = 256;
constexpr int E  = 4;
constexpr int H1 = 8;
constexpr int H2 = 4;
constexpr int NW  = 4;        // waves per block
constexpr int NP  = S / 2;    // 128 key pairs
constexpr int PPW = NP / NW;  // 32 pairs per wave
constexpr int R   = 4;        // rows per lane

typedef float v2f __attribute__((ext_vector_type(2)));

__device__ __forceinline__ v2f fma2(v2f a, v2f b, v2f c) {
    return __builtin_elementwise_fma(a, b, c);
}
__device__ __forceinline__ float fast_tanh(float x) {
    const float z = __builtin_amdgcn_exp2f(x * 2.88539008f);  // e^(2x)
    return 1.f - 2.f * __builtin_amdgcn_rcpf(z + 1.f);        // inf-safe
}

__global__ __launch_bounds__(256, 4) void attn_mlp_kernel(
    const float* __restrict__ x,
    const float* __restrict__ Wq, const float* __restrict__ Wk, const float* __restrict__ Wv,
    const float* __restrict__ W1, const float* __restrict__ b1,
    const float* __restrict__ W2, const float* __restrict__ b2,
    const float* __restrict__ W3, const float* __restrict__ b3,
    float* __restrict__ out)
{
    const int b    = blockIdx.x;
    const int tid  = threadIdx.x;
    const int w    = tid >> 6;
    const int lane = tid & 63;

    __shared__ float4 q_lds[S];                       // 4 KB
    __shared__ __align__(16) float kp_lds[NP][E][2];  // 4 KB pair-transposed
    __shared__ __align__(16) float vp_lds[NP][E][2];  // 4 KB
    __shared__ float4 acc_lds[NW][S];                 // 16 KB
    __shared__ float  l_lds[NW][S];                   // 4 KB
    __shared__ float  kmax_lds[NW];

    // ---- Phase 1: q/k/v for row tid; pair-transposed k/v ----
    const float4 xr = *reinterpret_cast<const float4*>(x + ((size_t)b * S + tid) * E);
    const float xv[E] = {xr.x, xr.y, xr.z, xr.w};
    {
        const int jp = tid >> 1, c = tid & 1;
        float4 q;
        float* qp = &q.x;
        float kk = 0.f;
        #pragma unroll
        for (int e = 0; e < E; ++e) {
            float aq = 0.f, ak = 0.f, av = 0.f;
            #pragma unroll
            for (int i = 0; i < E; ++i) {
                aq = fmaf(xv[i], Wq[i * E + e], aq);
                ak = fmaf(xv[i], Wk[i * E + e], ak);
                av = fmaf(xv[i], Wv[i * E + e], av);
            }
            qp[e] = aq * (0.5f * 1.44269504f);  // fold 1/sqrt(E), log2(e)
            kp_lds[jp][e][c] = ak;
            vp_lds[jp][e][c] = av;
            kk = fmaf(ak, ak, kk);
        }
        q_lds[tid] = q;

        #pragma unroll
        for (int off = 32; off > 0; off >>= 1)
            kk = fmaxf(kk, __shfl_xor(kk, off));
        if (lane == 0) kmax_lds[w] = kk;
    }
    __syncthreads();

    const float kmax2 = fmaxf(fmaxf(kmax_lds[0], kmax_lds[1]),
                              fmaxf(kmax_lds[2], kmax_lds[3]));

    // ---- per-lane rows {lane + 64*rr}: splat q and -m_hat into pairs ----
    v2f qx2[R], qy2[R], qz2[R], qw2[R], mh2[R];
    #pragma unroll
    for (int rr = 0; rr < R; ++rr) {
        const float4 q = q_lds[lane + 64 * rr];
        const float qq = fmaf(q.x, q.x, fmaf(q.y, q.y, fmaf(q.z, q.z, q.w * q.w)));
        const float mh = sqrtf(qq * kmax2);  // >= every scaled score
        qx2[rr] = v2f{q.x, q.x};
        qy2[rr] = v2f{q.y, q.y};
        qz2[rr] = v2f{q.z, q.z};
        qw2[rr] = v2f{q.w, q.w};
        mh2[rr] = v2f{-mh, -mh};
    }

    v2f l2[R], a0[R], a1[R], a2[R], a3[R];
    #pragma unroll
    for (int rr = 0; rr < R; ++rr) {
        l2[rr] = v2f{0.f, 0.f};
        a0[rr] = a1[rr] = a2[rr] = a3[rr] = v2f{0.f, 0.f};
    }

    // ---- Phase 2: scan this wave's 32 key pairs (wide b128 reads) ----
    const int p0 = w * PPW;
    #pragma unroll 4
    for (int jp = p0; jp < p0 + PPW; ++jp) {
        const float4* kf = reinterpret_cast<const float4*>(&kp_lds[jp][0][0]);
        const float4* vf = reinterpret_cast<const float4*>(&vp_lds[jp][0][0]);
        const float4 k01 = kf[0], k23 = kf[1];   // ds_read_b128 x2
        const float4 v01 = vf[0], v23 = vf[1];   // ds_read_b128 x2
        const v2f kx = {k01.x, k01.y}, ky = {k01.z, k01.w};
        const v2f kz = {k23.x, k23.y}, kw = {k23.z, k23.w};
        const v2f vx = {v01.x, v01.y}, vy = {v01.z, v01.w};
        const v2f vz = {v23.x, v23.y}, vw = {v23.z, v23.w};
        #pragma unroll
        for (int rr = 0; rr < R; ++rr) {
            v2f s2 = fma2(qw2[rr], kw, mh2[rr]);
            s2 = fma2(qz2[rr], kz, s2);
            s2 = fma2(qy2[rr], ky, s2);
            s2 = fma2(qx2[rr], kx, s2);
            const v2f p2 = {__builtin_amdgcn_exp2f(s2.x),
                            __builtin_amdgcn_exp2f(s2.y)};  // s2 <= 0
            l2[rr] += p2;
            a0[rr] = fma2(p2, vx, a0[rr]);
            a1[rr] = fma2(p2, vy, a1[rr]);
            a2[rr] = fma2(p2, vz, a2[rr]);
            a3[rr] = fma2(p2, vw, a3[rr]);
        }
    }

    // ---- merge partials: plain per-wave stores, no atomics ----
    #pragma unroll
    for (int rr = 0; rr < R; ++rr) {
        const int row = lane + 64 * rr;
        acc_lds[w][row] = make_float4(a0[rr].x + a0[rr].y,
                                      a1[rr].x + a1[rr].y,
                                      a2[rr].x + a2[rr].y,
                                      a3[rr].x + a3[rr].y);
        l_lds[w][row] = l2[rr].x + l2[rr].y;
    }
    __syncthreads();

    // ---- Phase 3: plain-sum merge for row tid, then MLP ----
    float lsum = 0.f;
    float ax = 0.f, ay = 0.f, az = 0.f, aw = 0.f;
    #pragma unroll
    for (int ww = 0; ww < NW; ++ww) {
        lsum += l_lds[ww][tid];
        const float4 a4 = acc_lds[ww][tid];
        ax += a4.x; ay += a4.y; az += a4.z; aw += a4.w;
    }
    const float inv = 1.0f / lsum;
    const float a[E] = {ax * inv, ay * inv, az * inv, aw * inv};

    float h1[H1];
    #pragma unroll
    for (int o = 0; o < H1; ++o) {
        float s = b1[o];
        #pragma unroll
        for (int i = 0; i < E; ++i) s = fmaf(a[i], W1[i * H1 + o], s);
        h1[o] = fast_tanh(s);
    }
    float h2[H2];
    #pragma unroll
    for (int o = 0; o < H2; ++o) {
        float s = b2[o];
        #pragma unroll
        for (int i = 0; i < H1; ++i) s = fmaf(h1[i], W2[i * H2 + o], s);
        h2[o] = fast_tanh(s);
    }
    float r = b3[0];
    #pragma unroll
    for (int i = 0; i < H2; ++i) r = fmaf(h2[i], W3[i], r);

    out[(size_t)b * S + tid] = r;
}

extern "C" void kernel_launch(void* const* d_in, const int* in_sizes, int n_in,
                              void* d_out, int out_size, void* d_ws, size_t ws_size,
                              hipStream_t stream) {
    const float* x  = (const float*)d_in[0];
    const float* Wq = (const float*)d_in[1];
    const float* Wk = (const float*)d_in[2];
    const float* Wv = (const float*)d_in[3];
    const float* W1 = (const float*)d_in[4];
    const float* b1 = (const float*)d_in[5];
    const float* W2 = (const float*)d_in[6];
    const float* b2 = (const float*)d_in[7];
    const float* W3 = (const float*)d_in[8];
    const float* b3 = (const float*)d_in[9];
    float* out = (float*)d_out;

    const int B = in_sizes[0] / (S * E);   // 1024
    attn_mlp_kernel<<<dim3(B), dim3(256), 0, stream>>>(
        x, Wq, Wk, Wv, W1, b1, W2, b2, W3, b3, out);
}